// Round 3
// baseline (437.227 us; speedup 1.0000x reference)
//
#include <hip/hip_runtime.h>
#include <hip/hip_bf16.h>
#include <math.h>

#define NNODES 100000
#define NEDGES 20000
#define NNZ_   2000000
#define FDIM   128
#define BN_EPS 1e-5f

// ---- bucket-sort geometry ----
#define NBUCK 256
#define CAP   9216        // per-bucket capacity (mean ~7812, sigma ~88 -> +16 sigma)
#define BPB_E 79          // edges/bucket (edge dir); bins/bucket = 79*8 = 632
#define BPB_N 391         // bins/bucket, node dir
#define SH_E  17          // edge entry = (e<<17)|n
#define SH_N  15          // node entry = (n<<15)|e
#define NPART 8           // node-table slices (one per XCD)
#define PSLICE 12500      // rows per slice -> 12500*256B = 3.2 MB < 4 MiB XCD L2

typedef __attribute__((ext_vector_type(8))) short bf16x8_t;
typedef __attribute__((ext_vector_type(4))) float f32x4_t;
typedef __attribute__((ext_vector_type(8))) unsigned short u16x8_t;

__device__ __forceinline__ float sigmoidf_(float x) {
    return 1.0f / (1.0f + __expf(-x));
}
__device__ __forceinline__ float bf2f(unsigned short u) {
    return __uint_as_float(((unsigned)u) << 16);
}
__device__ __forceinline__ unsigned short f2bf(float f) {
    __hip_bfloat16 h = __float2bfloat16(f);   // RNE
    return *reinterpret_cast<unsigned short*>(&h);
}

// ---- prep: bf16 copy of W_nh (B-operand layout = as-is) + transpose W_en ----
__global__ __launch_bounds__(256) void prep_w(
    const float* __restrict__ W_nh, const float* __restrict__ W_en,
    unsigned short* __restrict__ Wnh_bf, float* __restrict__ WTen)
{
    int idx = blockIdx.x * blockDim.x + threadIdx.x;
    if (idx < FDIM * FDIM) {
        Wnh_bf[idx] = f2bf(W_nh[idx]);
    } else {
        int j = idx - FDIM * FDIM;
        if (j >= 2 * FDIM * FDIM) return;
        int k = j >> 7, c = j & 127;
        WTen[j] = W_en[c * 2 * FDIM + k];
    }
}

// ---- GEMM1 via MFMA: out[100000,128] = sigmoid(x0 @ W_nh^T + b), bf16 out ----
__global__ __launch_bounds__(256) void gemm1_mfma(
    const float* __restrict__ x0, const unsigned short* __restrict__ Wb,
    const float* __restrict__ bias, unsigned short* __restrict__ out)
{
    __shared__ unsigned short As[32][FDIM + 8];
    const int tid  = threadIdx.x;
    const int row0 = blockIdx.x * 32;
    {
        int r = tid >> 3, c0 = (tid & 7) * 16;
        const float* src = x0 + (size_t)(row0 + r) * FDIM + c0;
        unsigned short* dst = &As[r][c0];
        #pragma unroll
        for (int i = 0; i < 4; i++) {
            float4 v = *(const float4*)(src + i * 4);
            dst[i * 4 + 0] = f2bf(v.x);
            dst[i * 4 + 1] = f2bf(v.y);
            dst[i * 4 + 2] = f2bf(v.z);
            dst[i * 4 + 3] = f2bf(v.w);
        }
    }
    __syncthreads();
    const int wave  = tid >> 6;
    const int lane  = tid & 63;
    const int mhalf = wave & 1;
    const int nhalf = wave >> 1;
    const int lm    = lane & 15;
    const int quad  = lane >> 4;
    f32x4_t acc[4] = {};
    #pragma unroll
    for (int ks = 0; ks < 4; ks++) {
        bf16x8_t a = *(const bf16x8_t*)&As[mhalf * 16 + lm][ks * 32 + quad * 8];
        #pragma unroll
        for (int nt = 0; nt < 4; nt++) {
            int n = nhalf * 64 + nt * 16 + lm;
            bf16x8_t b = *(const bf16x8_t*)(Wb + (size_t)n * FDIM + ks * 32 + quad * 8);
            acc[nt] = __builtin_amdgcn_mfma_f32_16x16x32_bf16(a, b, acc[nt], 0, 0, 0);
        }
    }
    const int mbase = row0 + mhalf * 16 + quad * 4;
    #pragma unroll
    for (int nt = 0; nt < 4; nt++) {
        int n = nhalf * 64 + nt * 16 + lm;
        float bv = bias[n];
        #pragma unroll
        for (int r2 = 0; r2 < 4; r2++) {
            out[(size_t)(mbase + r2) * FDIM + n] = f2bf(sigmoidf_(acc[nt][r2] + bv));
        }
    }
}

// ---- GEMM2 (fp32 vector): out = sigmoid(cat(x1,B) @ W_en^T + b), bf16 out ----
__global__ __launch_bounds__(256, 2) void gemm_sig_bf16(
    const float* __restrict__ A1, const float* __restrict__ A2,
    const float* __restrict__ WT, const float* __restrict__ bias,
    unsigned short* __restrict__ out)
{
    constexpr int K = 256, BK = 64;
    __shared__ float As[32][BK + 4];
    __shared__ float Ws[BK][FDIM];
    const int tid  = threadIdx.x;
    const int row0 = blockIdx.x * 32;
    const int tcol = tid & 31;
    const int trow = tid >> 5;
    float acc[4][4] = {};
    for (int kk = 0; kk < K; kk += BK) {
        const float* Asrc = (kk < FDIM) ? A1 : A2;
        const int koff    = (kk < FDIM) ? kk : kk - FDIM;
        #pragma unroll
        for (int i = 0; i < 2; i++) {
            int l = tid + i * 256;
            int r = l >> 4, j = l & 15;
            float4 v = *(const float4*)(Asrc + (size_t)(row0 + r) * FDIM + koff + j * 4);
            *(float4*)&As[r][j * 4] = v;
        }
        #pragma unroll
        for (int i = 0; i < 8; i++) {
            int l = tid + i * 256;
            int k = l >> 5, j = l & 31;
            float4 v = *(const float4*)(WT + (size_t)(kk + k) * FDIM + j * 4);
            *(float4*)&Ws[k][j * 4] = v;
        }
        __syncthreads();
        #pragma unroll
        for (int k = 0; k < BK; k += 4) {
            float4 a[4];
            #pragma unroll
            for (int r = 0; r < 4; r++)
                a[r] = *(const float4*)&As[trow * 4 + r][k];
            #pragma unroll
            for (int kq = 0; kq < 4; kq++) {
                float4 w = *(const float4*)&Ws[k + kq][tcol * 4];
                #pragma unroll
                for (int r = 0; r < 4; r++) {
                    float av = (kq == 0) ? a[r].x : (kq == 1) ? a[r].y
                             : (kq == 2) ? a[r].z : a[r].w;
                    acc[r][0] += av * w.x;
                    acc[r][1] += av * w.y;
                    acc[r][2] += av * w.z;
                    acc[r][3] += av * w.w;
                }
            }
        }
        __syncthreads();
    }
    float4 bv = *(const float4*)(bias + tcol * 4);
    #pragma unroll
    for (int r = 0; r < 4; r++) {
        int row = row0 + trow * 4 + r;
        ushort4 o;
        o.x = f2bf(sigmoidf_(acc[r][0] + bv.x));
        o.y = f2bf(sigmoidf_(acc[r][1] + bv.y));
        o.z = f2bf(sigmoidf_(acc[r][2] + bv.z));
        o.w = f2bf(sigmoidf_(acc[r][3] + bv.w));
        *(ushort4*)(out + (size_t)row * FDIM + tcol * 4) = o;
    }
}

// ---- Pass A: coarse bucket partition (both directions in one pass) ----
__global__ __launch_bounds__(1024) void bucket_scatter(
    const int* __restrict__ ni, const int* __restrict__ ei,
    unsigned* __restrict__ buck_e, unsigned* __restrict__ buck_n,
    int* __restrict__ gcur_e, int* __restrict__ gcur_n)
{
    __shared__ int lh_e[NBUCK], lh_n[NBUCK], lb_e[NBUCK], lb_n[NBUCK];
    const int t = threadIdx.x;
    if (t < NBUCK) { lh_e[t] = 0; lh_n[t] = 0; }
    __syncthreads();
    unsigned ent_e[4], ent_n[4];
    int be[4], bn[4], re[4], rn[4];
    const int base = blockIdx.x * 4096;
    #pragma unroll
    for (int j = 0; j < 4; j++) {
        int i = base + j * 1024 + t;
        if (i < NNZ_) {
            unsigned n = (unsigned)ni[i], e = (unsigned)ei[i];
            ent_e[j] = (e << SH_E) | n;  be[j] = (int)(e / BPB_E);
            ent_n[j] = (n << SH_N) | e;  bn[j] = (int)(n / BPB_N);
            re[j] = atomicAdd(&lh_e[be[j]], 1);
            rn[j] = atomicAdd(&lh_n[bn[j]], 1);
        } else { be[j] = -1; }
    }
    __syncthreads();
    if (t < NBUCK) {
        lb_e[t] = t * CAP + atomicAdd(&gcur_e[t], lh_e[t]);
        lb_n[t] = t * CAP + atomicAdd(&gcur_n[t], lh_n[t]);
    }
    __syncthreads();
    #pragma unroll
    for (int j = 0; j < 4; j++) {
        if (be[j] >= 0) {
            buck_e[(size_t)lb_e[be[j]] + re[j]] = ent_e[j];
            buck_n[(size_t)lb_n[bn[j]] + rn[j]] = ent_n[j];
        }
    }
}

// ---- Pass B, edge dir: sort bucket into (e,p)-bins; p = n/PSLICE ----
__device__ __forceinline__ int ep_bin(unsigned ent) {
    int e = (int)(ent >> SH_E);
    int n = (int)(ent & 0x1FFFFu);
    return e * NPART + n / PSLICE;
}

__device__ __forceinline__ void sort_bucket_e(
    const unsigned* __restrict__ region, int cnt, int gbase, int bucket,
    unsigned* __restrict__ csr, int* __restrict__ off)
{
    __shared__ unsigned lh[768];
    __shared__ unsigned lw[4];
    const int t = threadIdx.x;
    lh[t] = 0; lh[t + 256] = 0; lh[t + 512] = 0;
    __syncthreads();
    const int b0 = bucket * (BPB_E * NPART);
    for (int i = t; i < cnt; i += 256)
        atomicAdd(&lh[ep_bin(region[i]) - b0], 1u);
    __syncthreads();
    unsigned h0 = lh[3 * t], h1 = lh[3 * t + 1], h2 = lh[3 * t + 2];
    unsigned s = h0 + h1 + h2, inc = s;
    const int lane = t & 63;
    #pragma unroll
    for (int d = 1; d <= 32; d <<= 1) {
        unsigned v = (unsigned)__shfl_up((int)inc, d, 64);
        if (lane >= d) inc += v;
    }
    if (lane == 63) lw[t >> 6] = inc;
    __syncthreads();
    unsigned pre = 0;
    #pragma unroll
    for (int w = 0; w < 4; w++) if (w < (t >> 6)) pre += lw[w];
    unsigned excl = pre + inc - s;
    unsigned c0 = (unsigned)gbase + excl, c1 = c0 + h0, c2 = c1 + h1;
    lh[3 * t] = c0; lh[3 * t + 1] = c1; lh[3 * t + 2] = c2;
    #pragma unroll
    for (int j = 0; j < 3; j++) {
        int ib = 3 * t + j;
        unsigned cc = (j == 0) ? c0 : (j == 1) ? c1 : c2;
        if (ib <= BPB_E * NPART && b0 + ib <= NEDGES * NPART) off[b0 + ib] = (int)cc;
    }
    __syncthreads();
    for (int i = t; i < cnt; i += 256) {
        unsigned ent = region[i];
        unsigned pos = atomicAdd(&lh[ep_bin(ent) - b0], 1u);
        csr[pos] = ent & 0x1FFFFu;
    }
}

// ---- Pass B, node dir: 2 bins/thread ----
__device__ __forceinline__ void sort_bucket_n(
    const unsigned* __restrict__ region, int cnt, int gbase, int b0,
    unsigned short* __restrict__ csr, int* __restrict__ off)
{
    __shared__ unsigned lh[512];
    __shared__ unsigned lw[4];
    const int t = threadIdx.x;
    lh[t] = 0; lh[t + 256] = 0;
    __syncthreads();
    for (int i = t; i < cnt; i += 256) {
        int bin = (int)(region[i] >> SH_N) - b0;
        atomicAdd(&lh[bin], 1u);
    }
    __syncthreads();
    unsigned h0 = lh[2 * t], h1 = lh[2 * t + 1];
    unsigned s = h0 + h1, inc = s;
    const int lane = t & 63;
    #pragma unroll
    for (int d = 1; d <= 32; d <<= 1) {
        unsigned v = (unsigned)__shfl_up((int)inc, d, 64);
        if (lane >= d) inc += v;
    }
    if (lane == 63) lw[t >> 6] = inc;
    __syncthreads();
    unsigned pre = 0;
    #pragma unroll
    for (int w = 0; w < 4; w++) if (w < (t >> 6)) pre += lw[w];
    unsigned excl = pre + inc - s;
    unsigned c0 = (unsigned)gbase + excl;
    unsigned c1 = c0 + h0;
    lh[2 * t] = c0; lh[2 * t + 1] = c1;
    int i0 = 2 * t, i1 = 2 * t + 1;
    if (i0 <= BPB_N && b0 + i0 <= NNODES) off[b0 + i0] = (int)c0;
    if (i1 <= BPB_N && b0 + i1 <= NNODES) off[b0 + i1] = (int)c1;
    __syncthreads();
    for (int i = t; i < cnt; i += 256) {
        unsigned ent = region[i];
        int bin = (int)(ent >> SH_N) - b0;
        unsigned pos = atomicAdd(&lh[bin], 1u);
        csr[pos] = (unsigned short)(ent & 0x7FFFu);
    }
}

__global__ __launch_bounds__(256) void bucket_sort(
    const unsigned* __restrict__ buck_e, const unsigned* __restrict__ buck_n,
    const int* __restrict__ gcur_e, const int* __restrict__ gcur_n,
    unsigned* __restrict__ csr_e, unsigned short* __restrict__ csr_n,
    int* __restrict__ off_ep, int* __restrict__ off_n)
{
    const int b = blockIdx.x & 255;
    const int* gc = (blockIdx.x < 256) ? gcur_e : gcur_n;
    __shared__ int ws4[4];
    const int t = threadIdx.x;
    int v = (t < b) ? gc[t] : 0;
    #pragma unroll
    for (int d = 32; d > 0; d >>= 1) v += __shfl_down(v, d, 64);
    if ((t & 63) == 0) ws4[t >> 6] = v;
    __syncthreads();
    const int gbase = ws4[0] + ws4[1] + ws4[2] + ws4[3];
    const int cnt = gc[b];
    __syncthreads();
    if (blockIdx.x < 256)
        sort_bucket_e(buck_e + (size_t)b * CAP, cnt, gbase, b, csr_e, off_ep);
    else
        sort_bucket_n(buck_n + (size_t)b * CAP, cnt, gbase, b * BPB_N, csr_n, off_n);
}

// ---- XCD-affine partial gather: wave = (edge e, slice p); blockIdx = c*8+p ----
// Slice-p blocks gather only rows [p*PSLICE,(p+1)*PSLICE): 3.2 MB, L2-resident
// on XCD p. nt stores on partials keep the 82 MB write stream from evicting
// the table slice out of the XCD L2.
__global__ __launch_bounds__(256) void seg_part_gather(
    const unsigned short* __restrict__ table, const unsigned* __restrict__ csr,
    const int* __restrict__ off_ep, float* __restrict__ partial)
{
    const int p = blockIdx.x & 7;
    const int e = (blockIdx.x >> 3) * 4 + (threadIdx.x >> 6);
    const int lane = threadIdx.x & 63;
    const int sub  = lane >> 4;
    const int c8   = (lane & 15) * 8;
    const int bin  = e * NPART + p;
    const int i0 = off_ep[bin], i1 = off_ep[bin + 1];
    f32x4_t a0 = {}, a1 = {};
    for (int i = i0; i < i1; i += 16) {
        u16x8_t v[4];
        #pragma unroll
        for (int u = 0; u < 4; u++) {
            int row_i = i + 4 * u + sub;
            u16x8_t z = {};
            v[u] = z;
            if (row_i < i1) {
                int r = (int)__builtin_nontemporal_load(&csr[row_i]);
                v[u] = *(const u16x8_t*)(table + (size_t)r * FDIM + c8);
            }
        }
        #pragma unroll
        for (int u = 0; u < 4; u++) {
            a0[0] += bf2f(v[u][0]); a0[1] += bf2f(v[u][1]);
            a0[2] += bf2f(v[u][2]); a0[3] += bf2f(v[u][3]);
            a1[0] += bf2f(v[u][4]); a1[1] += bf2f(v[u][5]);
            a1[2] += bf2f(v[u][6]); a1[3] += bf2f(v[u][7]);
        }
    }
    #pragma unroll
    for (int j = 0; j < 4; j++) {
        a0[j] += __shfl_xor(a0[j], 16, 64);
        a0[j] += __shfl_xor(a0[j], 32, 64);
        a1[j] += __shfl_xor(a1[j], 16, 64);
        a1[j] += __shfl_xor(a1[j], 32, 64);
    }
    if (sub < 2) {
        const int q = c8 + sub * 4;
        f32x4_t s = sub ? a1 : a0;
        __builtin_nontemporal_store(s,
            (f32x4_t*)(partial + ((size_t)p * NEDGES + e) * FDIM + q));
    }
}

// ---- streaming 8-way partial reduce + B write + fused out1 finalize ----
__global__ __launch_bounds__(256) void reduce_fin(
    const float* __restrict__ part, const float* __restrict__ x1,
    const float* __restrict__ g, const float* __restrict__ bb,
    const float* __restrict__ mm, const float* __restrict__ vv,
    float* __restrict__ B, float* __restrict__ out1)
{
    const int idx = blockIdx.x * 256 + threadIdx.x;   // one f32x4 per thread
    if (idx >= NEDGES * (FDIM / 4)) return;
    const size_t q = (size_t)idx * 4;
    f32x4_t s = {};
    #pragma unroll
    for (int p = 0; p < NPART; p++)
        s += __builtin_nontemporal_load(
                 (const f32x4_t*)(part + (size_t)p * NEDGES * FDIM + q));
    __builtin_nontemporal_store(s, (f32x4_t*)(B + q));
    const int col = (idx & 31) * 4;
    f32x4_t xv = __builtin_nontemporal_load((const f32x4_t*)(x1 + q));
    f32x4_t gg = *(const f32x4_t*)(g + col);
    f32x4_t bt = *(const f32x4_t*)(bb + col);
    f32x4_t mn = *(const f32x4_t*)(mm + col);
    f32x4_t vr = *(const f32x4_t*)(vv + col);
    f32x4_t o;
    #pragma unroll
    for (int j = 0; j < 4; j++)
        o[j] = sigmoidf_((xv[j] - mn[j]) * (gg[j] * rsqrtf(vr[j] + BN_EPS))
                         + bt[j] + s[j]);
    __builtin_nontemporal_store(o, (f32x4_t*)(out1 + q));
}

// ---- segmented sum v2 (node dir + edge fallback): one wave/segment, deep ILP ----
// nt on csr loads, x load, and output stores: keeps the gather table cached.
template<typename IDX, int U, int OFFSTR>
__global__ __launch_bounds__(256) void seg_sum_fin_v2(
    const unsigned short* __restrict__ table, const IDX* __restrict__ csr,
    const int* __restrict__ off, const float* __restrict__ x,
    const float* __restrict__ g, const float* __restrict__ bb,
    const float* __restrict__ mm, const float* __restrict__ vv,
    float* __restrict__ agg_out, float* __restrict__ fin_out, int nseg)
{
    const int seg = blockIdx.x * 4 + (threadIdx.x >> 6);
    if (seg >= nseg) return;
    const int lane = threadIdx.x & 63;
    const int c    = lane & 15;
    const int sub  = lane >> 4;
    const int c8   = c * 8;

    const int i0 = off[seg * OFFSTR], i1 = off[seg * OFFSTR + OFFSTR];
    f32x4_t a0 = {}, a1 = {};

    int i = i0;
    for (; i + 4 * U <= i1; i += 4 * U) {
        int r[U];
        u16x8_t v[U];
        #pragma unroll
        for (int u = 0; u < U; u++)
            r[u] = (int)__builtin_nontemporal_load(&csr[i + 4 * u + sub]);
        #pragma unroll
        for (int u = 0; u < U; u++)
            v[u] = *(const u16x8_t*)(table + (size_t)r[u] * FDIM + c8);
        #pragma unroll
        for (int u = 0; u < U; u++) {
            a0[0] += bf2f(v[u][0]); a0[1] += bf2f(v[u][1]);
            a0[2] += bf2f(v[u][2]); a0[3] += bf2f(v[u][3]);
            a1[0] += bf2f(v[u][4]); a1[1] += bf2f(v[u][5]);
            a1[2] += bf2f(v[u][6]); a1[3] += bf2f(v[u][7]);
        }
    }
    if (i < i1) {
        u16x8_t v[U];
        #pragma unroll
        for (int u = 0; u < U; u++) {
            int row = i + 4 * u + sub;
            u16x8_t z = {};
            v[u] = z;
            if (row < i1)
                v[u] = *(const u16x8_t*)(table + (size_t)csr[row] * FDIM + c8);
        }
        #pragma unroll
        for (int u = 0; u < U; u++) {
            a0[0] += bf2f(v[u][0]); a0[1] += bf2f(v[u][1]);
            a0[2] += bf2f(v[u][2]); a0[3] += bf2f(v[u][3]);
            a1[0] += bf2f(v[u][4]); a1[1] += bf2f(v[u][5]);
            a1[2] += bf2f(v[u][6]); a1[3] += bf2f(v[u][7]);
        }
    }

    #pragma unroll
    for (int j = 0; j < 4; j++) {
        a0[j] += __shfl_xor(a0[j], 16, 64);
        a0[j] += __shfl_xor(a0[j], 32, 64);
        a1[j] += __shfl_xor(a1[j], 16, 64);
        a1[j] += __shfl_xor(a1[j], 32, 64);
    }

    if (sub < 2) {
        const int q = c8 + sub * 4;
        f32x4_t s = sub ? a1 : a0;
        if (agg_out)
            __builtin_nontemporal_store(s, (f32x4_t*)(agg_out + (size_t)seg * FDIM + q));
        if (fin_out) {
            f32x4_t xv = __builtin_nontemporal_load(
                             (const f32x4_t*)(x + (size_t)seg * FDIM + q));
            f32x4_t gg = *(const f32x4_t*)(g + q);
            f32x4_t bt = *(const f32x4_t*)(bb + q);
            f32x4_t mn = *(const f32x4_t*)(mm + q);
            f32x4_t vr = *(const f32x4_t*)(vv + q);
            f32x4_t o;
            #pragma unroll
            for (int j = 0; j < 4; j++)
                o[j] = sigmoidf_((xv[j] - mn[j]) * (gg[j] * rsqrtf(vr[j] + BN_EPS))
                                 + bt[j] + s[j]);
            __builtin_nontemporal_store(o, (f32x4_t*)(fin_out + (size_t)seg * FDIM + q));
        }
    }
}

extern "C" void kernel_launch(void* const* d_in, const int* in_sizes, int n_in,
                              void* d_out, int out_size, void* d_ws, size_t ws_size,
                              hipStream_t stream)
{
    const float* x0       = (const float*)d_in[0];
    const float* x1       = (const float*)d_in[1];
    const int*   node_idx = (const int*)d_in[2];
    const int*   edge_idx = (const int*)d_in[3];
    const float* W_nh     = (const float*)d_in[4];
    const float* b_nh     = (const float*)d_in[5];
    const float* W_en     = (const float*)d_in[6];
    const float* b_en     = (const float*)d_in[7];
    const float* bn0g = (const float*)d_in[8];
    const float* bn0b = (const float*)d_in[9];
    const float* bn0m = (const float*)d_in[10];
    const float* bn0v = (const float*)d_in[11];
    const float* bn1g = (const float*)d_in[12];
    const float* bn1b = (const float*)d_in[13];
    const float* bn1m = (const float*)d_in[14];
    const float* bn1v = (const float*)d_in[15];

    float* ws = (float*)d_ws;
    float* B    = ws;                           // node_msg_agg fp32 [20000,128]
    float* WTen = B + (size_t)NEDGES * FDIM;    // [256,128] fp32
    unsigned short* Wnh_bf = (unsigned short*)(WTen + 2 * FDIM * FDIM); // [128,128] bf16
    unsigned short* A_bf = Wnh_bf + FDIM * FDIM;                  // [100000,128] bf16
    unsigned short* D_bf = A_bf + (size_t)NNODES * FDIM;          // [20000,128] bf16
    int* off_ep = (int*)(D_bf + (size_t)NEDGES * FDIM);     // 160001 (pad 160004)
    int* off_n  = off_ep + 160004;                          // 100001 (pad 100004)
    unsigned* csr_e = (unsigned*)(off_n + 100004);          // 2M u32
    unsigned short* csr_n = (unsigned short*)(csr_e + NNZ_);// 2M u16
    unsigned* buck_e = (unsigned*)(csr_n + NNZ_);           // [NBUCK*CAP]
    unsigned* buck_n = buck_e + (size_t)NBUCK * CAP;        // [NBUCK*CAP]
    int* gcur_e = (int*)(buck_n + (size_t)NBUCK * CAP);     // 256
    int* gcur_n = gcur_e + NBUCK;                           // 256
    // partials overlay the (dead-after-sort) bucket arrays: [8][20000][128] fp32
    float* partial = (float*)buck_e;
    const size_t need = ((char*)partial - (char*)d_ws)
                      + (size_t)NPART * NEDGES * FDIM * sizeof(float);
    const bool big = ws_size >= need;

    // --- CSR build via 2-level bucket sort (edge dir binned by (e, n/PSLICE)) ---
    hipMemsetAsync(gcur_e, 0, 2 * NBUCK * sizeof(int), stream);
    bucket_scatter<<<(NNZ_ + 4095) / 4096, 1024, 0, stream>>>(
        node_idx, edge_idx, buck_e, buck_n, gcur_e, gcur_n);
    bucket_sort<<<2 * NBUCK, 256, 0, stream>>>(buck_e, buck_n, gcur_e, gcur_n,
                                               csr_e, csr_n, off_ep, off_n);

    prep_w<<<(3 * FDIM * FDIM + 255) / 256, 256, 0, stream>>>(W_nh, W_en, Wnh_bf, WTen);

    float* out0 = (float*)d_out;
    float* out1 = out0 + (size_t)NNODES * FDIM;

    // node -> hyperedge: GEMM1 (MFMA, bf16 out)
    gemm1_mfma<<<NNODES / 32, 256, 0, stream>>>(x0, Wnh_bf, b_nh, A_bf);

    if (big) {
        // XCD-affine partial gather -> streaming reduce (+ out1 finalize) -> GEMM2
        seg_part_gather<<<(NEDGES / 4) * 8, 256, 0, stream>>>(
            A_bf, csr_e, off_ep, partial);
        reduce_fin<<<(NEDGES * (FDIM / 4) + 255) / 256, 256, 0, stream>>>(
            partial, x1, bn1g, bn1b, bn1m, bn1v, B, out1);
    } else {
        // fallback: edge segments span 8 adjacent bins
        seg_sum_fin_v2<unsigned, 8, NPART><<<(NEDGES + 3) / 4, 256, 0, stream>>>(
            A_bf, csr_e, off_ep, x1, bn1g, bn1b, bn1m, bn1v, B, out1, NEDGES);
    }
    gemm_sig_bf16<<<NEDGES / 32, 256, 0, stream>>>(x1, B, WTen, b_en, D_bf);

    // hyperedge -> node: pull-aggregate (+ fused x0_out)
    seg_sum_fin_v2<unsigned short, 4, 1><<<(NNODES + 3) / 4, 256, 0, stream>>>(
        D_bf, csr_n, off_n, x0, bn0g, bn0b, bn0m, bn0v, nullptr, out0, NNODES);
}

// Round 4
// 404.407 us; speedup vs baseline: 1.0812x; 1.0812x over previous
//
#include <hip/hip_runtime.h>
#include <hip/hip_bf16.h>
#include <math.h>

#define NNODES 100000
#define NEDGES 20000
#define NNZ_   2000000
#define FDIM   128
#define BN_EPS 1e-5f

// ---- bucket-sort geometry ----
#define NBUCK 256
#define CAP   9216        // per-bucket capacity (mean ~7812, sigma ~88 -> +16 sigma)
#define BPB_E 79          // edges/bucket (edge dir); bins/bucket = 79*8 = 632
#define BPB_N 391         // bins/bucket, node dir
#define SH_E  17          // edge entry = (e<<17)|n
#define SH_N  15          // node entry = (n<<15)|e
#define NPART 8           // node-table slices (one per XCD)
#define PSLICE 12500      // rows per slice -> 12500*256B = 3.2 MB < 4 MiB XCD L2

typedef __attribute__((ext_vector_type(8))) short bf16x8_t;
typedef __attribute__((ext_vector_type(4))) float f32x4_t;
typedef __attribute__((ext_vector_type(8))) unsigned short u16x8_t;

__device__ __forceinline__ float sigmoidf_(float x) {
    return 1.0f / (1.0f + __expf(-x));
}
__device__ __forceinline__ float bf2f(unsigned short u) {
    return __uint_as_float(((unsigned)u) << 16);
}
__device__ __forceinline__ unsigned short f2bf(float f) {
    __hip_bfloat16 h = __float2bfloat16(f);   // RNE
    return *reinterpret_cast<unsigned short*>(&h);
}

// ---- prep: bf16 copy of W_nh (B-operand layout = as-is) + transpose W_en ----
__global__ __launch_bounds__(256) void prep_w(
    const float* __restrict__ W_nh, const float* __restrict__ W_en,
    unsigned short* __restrict__ Wnh_bf, float* __restrict__ WTen)
{
    int idx = blockIdx.x * blockDim.x + threadIdx.x;
    if (idx < FDIM * FDIM) {
        Wnh_bf[idx] = f2bf(W_nh[idx]);
    } else {
        int j = idx - FDIM * FDIM;
        if (j >= 2 * FDIM * FDIM) return;
        int k = j >> 7, c = j & 127;
        WTen[j] = W_en[c * 2 * FDIM + k];
    }
}

// ---- GEMM1 via MFMA: out[100000,128] = sigmoid(x0 @ W_nh^T + b), bf16 out ----
__global__ __launch_bounds__(256) void gemm1_mfma(
    const float* __restrict__ x0, const unsigned short* __restrict__ Wb,
    const float* __restrict__ bias, unsigned short* __restrict__ out)
{
    __shared__ unsigned short As[32][FDIM + 8];
    const int tid  = threadIdx.x;
    const int row0 = blockIdx.x * 32;
    {
        int r = tid >> 3, c0 = (tid & 7) * 16;
        const float* src = x0 + (size_t)(row0 + r) * FDIM + c0;
        unsigned short* dst = &As[r][c0];
        #pragma unroll
        for (int i = 0; i < 4; i++) {
            float4 v = *(const float4*)(src + i * 4);
            dst[i * 4 + 0] = f2bf(v.x);
            dst[i * 4 + 1] = f2bf(v.y);
            dst[i * 4 + 2] = f2bf(v.z);
            dst[i * 4 + 3] = f2bf(v.w);
        }
    }
    __syncthreads();
    const int wave  = tid >> 6;
    const int lane  = tid & 63;
    const int mhalf = wave & 1;
    const int nhalf = wave >> 1;
    const int lm    = lane & 15;
    const int quad  = lane >> 4;
    f32x4_t acc[4] = {};
    #pragma unroll
    for (int ks = 0; ks < 4; ks++) {
        bf16x8_t a = *(const bf16x8_t*)&As[mhalf * 16 + lm][ks * 32 + quad * 8];
        #pragma unroll
        for (int nt = 0; nt < 4; nt++) {
            int n = nhalf * 64 + nt * 16 + lm;
            bf16x8_t b = *(const bf16x8_t*)(Wb + (size_t)n * FDIM + ks * 32 + quad * 8);
            acc[nt] = __builtin_amdgcn_mfma_f32_16x16x32_bf16(a, b, acc[nt], 0, 0, 0);
        }
    }
    const int mbase = row0 + mhalf * 16 + quad * 4;
    #pragma unroll
    for (int nt = 0; nt < 4; nt++) {
        int n = nhalf * 64 + nt * 16 + lm;
        float bv = bias[n];
        #pragma unroll
        for (int r2 = 0; r2 < 4; r2++) {
            out[(size_t)(mbase + r2) * FDIM + n] = f2bf(sigmoidf_(acc[nt][r2] + bv));
        }
    }
}

// ---- GEMM2 (fp32 vector): out = sigmoid(cat(x1,B) @ W_en^T + b), bf16 out ----
__global__ __launch_bounds__(256, 2) void gemm_sig_bf16(
    const float* __restrict__ A1, const float* __restrict__ A2,
    const float* __restrict__ WT, const float* __restrict__ bias,
    unsigned short* __restrict__ out)
{
    constexpr int K = 256, BK = 64;
    __shared__ float As[32][BK + 4];
    __shared__ float Ws[BK][FDIM];
    const int tid  = threadIdx.x;
    const int row0 = blockIdx.x * 32;
    const int tcol = tid & 31;
    const int trow = tid >> 5;
    float acc[4][4] = {};
    for (int kk = 0; kk < K; kk += BK) {
        const float* Asrc = (kk < FDIM) ? A1 : A2;
        const int koff    = (kk < FDIM) ? kk : kk - FDIM;
        #pragma unroll
        for (int i = 0; i < 2; i++) {
            int l = tid + i * 256;
            int r = l >> 4, j = l & 15;
            float4 v = *(const float4*)(Asrc + (size_t)(row0 + r) * FDIM + koff + j * 4);
            *(float4*)&As[r][j * 4] = v;
        }
        #pragma unroll
        for (int i = 0; i < 8; i++) {
            int l = tid + i * 256;
            int k = l >> 5, j = l & 31;
            float4 v = *(const float4*)(WT + (size_t)(kk + k) * FDIM + j * 4);
            *(float4*)&Ws[k][j * 4] = v;
        }
        __syncthreads();
        #pragma unroll
        for (int k = 0; k < BK; k += 4) {
            float4 a[4];
            #pragma unroll
            for (int r = 0; r < 4; r++)
                a[r] = *(const float4*)&As[trow * 4 + r][k];
            #pragma unroll
            for (int kq = 0; kq < 4; kq++) {
                float4 w = *(const float4*)&Ws[k + kq][tcol * 4];
                #pragma unroll
                for (int r = 0; r < 4; r++) {
                    float av = (kq == 0) ? a[r].x : (kq == 1) ? a[r].y
                             : (kq == 2) ? a[r].z : a[r].w;
                    acc[r][0] += av * w.x;
                    acc[r][1] += av * w.y;
                    acc[r][2] += av * w.z;
                    acc[r][3] += av * w.w;
                }
            }
        }
        __syncthreads();
    }
    float4 bv = *(const float4*)(bias + tcol * 4);
    #pragma unroll
    for (int r = 0; r < 4; r++) {
        int row = row0 + trow * 4 + r;
        ushort4 o;
        o.x = f2bf(sigmoidf_(acc[r][0] + bv.x));
        o.y = f2bf(sigmoidf_(acc[r][1] + bv.y));
        o.z = f2bf(sigmoidf_(acc[r][2] + bv.z));
        o.w = f2bf(sigmoidf_(acc[r][3] + bv.w));
        *(ushort4*)(out + (size_t)row * FDIM + tcol * 4) = o;
    }
}

// ---- Pass A: coarse bucket partition (both directions in one pass) ----
__global__ __launch_bounds__(1024) void bucket_scatter(
    const int* __restrict__ ni, const int* __restrict__ ei,
    unsigned* __restrict__ buck_e, unsigned* __restrict__ buck_n,
    int* __restrict__ gcur_e, int* __restrict__ gcur_n)
{
    __shared__ int lh_e[NBUCK], lh_n[NBUCK], lb_e[NBUCK], lb_n[NBUCK];
    const int t = threadIdx.x;
    if (t < NBUCK) { lh_e[t] = 0; lh_n[t] = 0; }
    __syncthreads();
    unsigned ent_e[4], ent_n[4];
    int be[4], bn[4], re[4], rn[4];
    const int base = blockIdx.x * 4096;
    #pragma unroll
    for (int j = 0; j < 4; j++) {
        int i = base + j * 1024 + t;
        if (i < NNZ_) {
            unsigned n = (unsigned)ni[i], e = (unsigned)ei[i];
            ent_e[j] = (e << SH_E) | n;  be[j] = (int)(e / BPB_E);
            ent_n[j] = (n << SH_N) | e;  bn[j] = (int)(n / BPB_N);
            re[j] = atomicAdd(&lh_e[be[j]], 1);
            rn[j] = atomicAdd(&lh_n[bn[j]], 1);
        } else { be[j] = -1; }
    }
    __syncthreads();
    if (t < NBUCK) {
        lb_e[t] = t * CAP + atomicAdd(&gcur_e[t], lh_e[t]);
        lb_n[t] = t * CAP + atomicAdd(&gcur_n[t], lh_n[t]);
    }
    __syncthreads();
    #pragma unroll
    for (int j = 0; j < 4; j++) {
        if (be[j] >= 0) {
            buck_e[(size_t)lb_e[be[j]] + re[j]] = ent_e[j];
            buck_n[(size_t)lb_n[bn[j]] + rn[j]] = ent_n[j];
        }
    }
}

// ---- Pass B, edge dir: sort bucket into (e,p)-bins; p = n/PSLICE ----
__device__ __forceinline__ int ep_bin(unsigned ent) {
    int e = (int)(ent >> SH_E);
    int n = (int)(ent & 0x1FFFFu);
    return e * NPART + n / PSLICE;
}

__device__ __forceinline__ void sort_bucket_e(
    const unsigned* __restrict__ region, int cnt, int gbase, int bucket,
    unsigned* __restrict__ csr, int* __restrict__ off)
{
    __shared__ unsigned lh[768];
    __shared__ unsigned lw[4];
    const int t = threadIdx.x;
    lh[t] = 0; lh[t + 256] = 0; lh[t + 512] = 0;
    __syncthreads();
    const int b0 = bucket * (BPB_E * NPART);
    for (int i = t; i < cnt; i += 256)
        atomicAdd(&lh[ep_bin(region[i]) - b0], 1u);
    __syncthreads();
    unsigned h0 = lh[3 * t], h1 = lh[3 * t + 1], h2 = lh[3 * t + 2];
    unsigned s = h0 + h1 + h2, inc = s;
    const int lane = t & 63;
    #pragma unroll
    for (int d = 1; d <= 32; d <<= 1) {
        unsigned v = (unsigned)__shfl_up((int)inc, d, 64);
        if (lane >= d) inc += v;
    }
    if (lane == 63) lw[t >> 6] = inc;
    __syncthreads();
    unsigned pre = 0;
    #pragma unroll
    for (int w = 0; w < 4; w++) if (w < (t >> 6)) pre += lw[w];
    unsigned excl = pre + inc - s;
    unsigned c0 = (unsigned)gbase + excl, c1 = c0 + h0, c2 = c1 + h1;
    lh[3 * t] = c0; lh[3 * t + 1] = c1; lh[3 * t + 2] = c2;
    #pragma unroll
    for (int j = 0; j < 3; j++) {
        int ib = 3 * t + j;
        unsigned cc = (j == 0) ? c0 : (j == 1) ? c1 : c2;
        if (ib <= BPB_E * NPART && b0 + ib <= NEDGES * NPART) off[b0 + ib] = (int)cc;
    }
    __syncthreads();
    for (int i = t; i < cnt; i += 256) {
        unsigned ent = region[i];
        unsigned pos = atomicAdd(&lh[ep_bin(ent) - b0], 1u);
        csr[pos] = ent & 0x1FFFFu;
    }
}

// ---- Pass B, node dir: 2 bins/thread ----
__device__ __forceinline__ void sort_bucket_n(
    const unsigned* __restrict__ region, int cnt, int gbase, int b0,
    unsigned short* __restrict__ csr, int* __restrict__ off)
{
    __shared__ unsigned lh[512];
    __shared__ unsigned lw[4];
    const int t = threadIdx.x;
    lh[t] = 0; lh[t + 256] = 0;
    __syncthreads();
    for (int i = t; i < cnt; i += 256) {
        int bin = (int)(region[i] >> SH_N) - b0;
        atomicAdd(&lh[bin], 1u);
    }
    __syncthreads();
    unsigned h0 = lh[2 * t], h1 = lh[2 * t + 1];
    unsigned s = h0 + h1, inc = s;
    const int lane = t & 63;
    #pragma unroll
    for (int d = 1; d <= 32; d <<= 1) {
        unsigned v = (unsigned)__shfl_up((int)inc, d, 64);
        if (lane >= d) inc += v;
    }
    if (lane == 63) lw[t >> 6] = inc;
    __syncthreads();
    unsigned pre = 0;
    #pragma unroll
    for (int w = 0; w < 4; w++) if (w < (t >> 6)) pre += lw[w];
    unsigned excl = pre + inc - s;
    unsigned c0 = (unsigned)gbase + excl;
    unsigned c1 = c0 + h0;
    lh[2 * t] = c0; lh[2 * t + 1] = c1;
    int i0 = 2 * t, i1 = 2 * t + 1;
    if (i0 <= BPB_N && b0 + i0 <= NNODES) off[b0 + i0] = (int)c0;
    if (i1 <= BPB_N && b0 + i1 <= NNODES) off[b0 + i1] = (int)c1;
    __syncthreads();
    for (int i = t; i < cnt; i += 256) {
        unsigned ent = region[i];
        int bin = (int)(ent >> SH_N) - b0;
        unsigned pos = atomicAdd(&lh[bin], 1u);
        csr[pos] = (unsigned short)(ent & 0x7FFFu);
    }
}

__global__ __launch_bounds__(256) void bucket_sort(
    const unsigned* __restrict__ buck_e, const unsigned* __restrict__ buck_n,
    const int* __restrict__ gcur_e, const int* __restrict__ gcur_n,
    unsigned* __restrict__ csr_e, unsigned short* __restrict__ csr_n,
    int* __restrict__ off_ep, int* __restrict__ off_n)
{
    const int b = blockIdx.x & 255;
    const int* gc = (blockIdx.x < 256) ? gcur_e : gcur_n;
    __shared__ int ws4[4];
    const int t = threadIdx.x;
    int v = (t < b) ? gc[t] : 0;
    #pragma unroll
    for (int d = 32; d > 0; d >>= 1) v += __shfl_down(v, d, 64);
    if ((t & 63) == 0) ws4[t >> 6] = v;
    __syncthreads();
    const int gbase = ws4[0] + ws4[1] + ws4[2] + ws4[3];
    const int cnt = gc[b];
    __syncthreads();
    if (blockIdx.x < 256)
        sort_bucket_e(buck_e + (size_t)b * CAP, cnt, gbase, b, csr_e, off_ep);
    else
        sort_bucket_n(buck_n + (size_t)b * CAP, cnt, gbase, b * BPB_N, csr_n, off_n);
}

// ---- XCD-affine partial gather v2: lean loop matched to ~12.5-row bins ----
// wave = (edge e, slice p); blockIdx = c*8+p pins slice p to XCD p.
// Unconditional 8-row step, unconditional 4-row step, <=3-row predicated tail.
// No nontemporal anywhere (nt was the R3 regression).
__global__ __launch_bounds__(256) void seg_part_gather(
    const unsigned short* __restrict__ table, const unsigned* __restrict__ csr,
    const int* __restrict__ off_ep, float* __restrict__ partial)
{
    const int p = blockIdx.x & 7;
    const int e = (blockIdx.x >> 3) * 4 + (threadIdx.x >> 6);
    const int lane = threadIdx.x & 63;
    const int sub  = lane >> 4;
    const int c8   = (lane & 15) * 8;
    const int bin  = e * NPART + p;
    const int i0 = off_ep[bin], i1 = off_ep[bin + 1];
    f32x4_t a0 = {}, a1 = {};
    int i = i0;
    for (; i + 8 <= i1; i += 8) {
        int r0 = (int)csr[i + sub];
        int r1 = (int)csr[i + 4 + sub];
        u16x8_t v0 = *(const u16x8_t*)(table + (size_t)r0 * FDIM + c8);
        u16x8_t v1 = *(const u16x8_t*)(table + (size_t)r1 * FDIM + c8);
        a0[0] += bf2f(v0[0]) + bf2f(v1[0]);
        a0[1] += bf2f(v0[1]) + bf2f(v1[1]);
        a0[2] += bf2f(v0[2]) + bf2f(v1[2]);
        a0[3] += bf2f(v0[3]) + bf2f(v1[3]);
        a1[0] += bf2f(v0[4]) + bf2f(v1[4]);
        a1[1] += bf2f(v0[5]) + bf2f(v1[5]);
        a1[2] += bf2f(v0[6]) + bf2f(v1[6]);
        a1[3] += bf2f(v0[7]) + bf2f(v1[7]);
    }
    if (i + 4 <= i1) {
        int r = (int)csr[i + sub];
        u16x8_t v = *(const u16x8_t*)(table + (size_t)r * FDIM + c8);
        a0[0] += bf2f(v[0]); a0[1] += bf2f(v[1]);
        a0[2] += bf2f(v[2]); a0[3] += bf2f(v[3]);
        a1[0] += bf2f(v[4]); a1[1] += bf2f(v[5]);
        a1[2] += bf2f(v[6]); a1[3] += bf2f(v[7]);
        i += 4;
    }
    if (i < i1 && sub < i1 - i) {
        int r = (int)csr[i + sub];
        u16x8_t v = *(const u16x8_t*)(table + (size_t)r * FDIM + c8);
        a0[0] += bf2f(v[0]); a0[1] += bf2f(v[1]);
        a0[2] += bf2f(v[2]); a0[3] += bf2f(v[3]);
        a1[0] += bf2f(v[4]); a1[1] += bf2f(v[5]);
        a1[2] += bf2f(v[6]); a1[3] += bf2f(v[7]);
    }
    #pragma unroll
    for (int j = 0; j < 4; j++) {
        a0[j] += __shfl_xor(a0[j], 16, 64);
        a0[j] += __shfl_xor(a0[j], 32, 64);
        a1[j] += __shfl_xor(a1[j], 16, 64);
        a1[j] += __shfl_xor(a1[j], 32, 64);
    }
    if (sub < 2) {
        const int q = c8 + sub * 4;
        f32x4_t s = sub ? a1 : a0;
        *(f32x4_t*)(partial + ((size_t)p * NEDGES + e) * FDIM + q) = s;
    }
}

// ---- streaming 8-way partial reduce + B write + fused out1 finalize ----
// nt only on pure streams (partial loads, out1 store); B stays cached for gemm.
__global__ __launch_bounds__(256) void reduce_fin(
    const float* __restrict__ part, const float* __restrict__ x1,
    const float* __restrict__ g, const float* __restrict__ bb,
    const float* __restrict__ mm, const float* __restrict__ vv,
    float* __restrict__ B, float* __restrict__ out1)
{
    const int idx = blockIdx.x * 256 + threadIdx.x;   // one f32x4 per thread
    if (idx >= NEDGES * (FDIM / 4)) return;
    const size_t q = (size_t)idx * 4;
    f32x4_t s = {};
    #pragma unroll
    for (int p = 0; p < NPART; p++)
        s += __builtin_nontemporal_load(
                 (const f32x4_t*)(part + (size_t)p * NEDGES * FDIM + q));
    *(f32x4_t*)(B + q) = s;
    const int col = (idx & 31) * 4;
    f32x4_t xv = *(const f32x4_t*)(x1 + q);
    f32x4_t gg = *(const f32x4_t*)(g + col);
    f32x4_t bt = *(const f32x4_t*)(bb + col);
    f32x4_t mn = *(const f32x4_t*)(mm + col);
    f32x4_t vr = *(const f32x4_t*)(vv + col);
    f32x4_t o;
    #pragma unroll
    for (int j = 0; j < 4; j++)
        o[j] = sigmoidf_((xv[j] - mn[j]) * (gg[j] * rsqrtf(vr[j] + BN_EPS))
                         + bt[j] + s[j]);
    __builtin_nontemporal_store(o, (f32x4_t*)(out1 + q));
}

// ---- segmented sum v2 (node dir + edge fallback): exact R1 body, no nt ----
template<typename IDX, int U, int OFFSTR>
__global__ __launch_bounds__(256) void seg_sum_fin_v2(
    const unsigned short* __restrict__ table, const IDX* __restrict__ csr,
    const int* __restrict__ off, const float* __restrict__ x,
    const float* __restrict__ g, const float* __restrict__ bb,
    const float* __restrict__ mm, const float* __restrict__ vv,
    float* __restrict__ agg_out, float* __restrict__ fin_out, int nseg)
{
    const int seg = blockIdx.x * 4 + (threadIdx.x >> 6);
    if (seg >= nseg) return;
    const int lane = threadIdx.x & 63;
    const int c    = lane & 15;
    const int sub  = lane >> 4;
    const int c8   = c * 8;

    const int i0 = off[seg * OFFSTR], i1 = off[seg * OFFSTR + OFFSTR];
    f32x4_t a0 = {}, a1 = {};

    int i = i0;
    for (; i + 4 * U <= i1; i += 4 * U) {
        int r[U];
        u16x8_t v[U];
        #pragma unroll
        for (int u = 0; u < U; u++) r[u] = (int)csr[i + 4 * u + sub];
        #pragma unroll
        for (int u = 0; u < U; u++)
            v[u] = *(const u16x8_t*)(table + (size_t)r[u] * FDIM + c8);
        #pragma unroll
        for (int u = 0; u < U; u++) {
            a0[0] += bf2f(v[u][0]); a0[1] += bf2f(v[u][1]);
            a0[2] += bf2f(v[u][2]); a0[3] += bf2f(v[u][3]);
            a1[0] += bf2f(v[u][4]); a1[1] += bf2f(v[u][5]);
            a1[2] += bf2f(v[u][6]); a1[3] += bf2f(v[u][7]);
        }
    }
    if (i < i1) {
        u16x8_t v[U];
        #pragma unroll
        for (int u = 0; u < U; u++) {
            int row = i + 4 * u + sub;
            u16x8_t z = {};
            v[u] = z;
            if (row < i1)
                v[u] = *(const u16x8_t*)(table + (size_t)csr[row] * FDIM + c8);
        }
        #pragma unroll
        for (int u = 0; u < U; u++) {
            a0[0] += bf2f(v[u][0]); a0[1] += bf2f(v[u][1]);
            a0[2] += bf2f(v[u][2]); a0[3] += bf2f(v[u][3]);
            a1[0] += bf2f(v[u][4]); a1[1] += bf2f(v[u][5]);
            a1[2] += bf2f(v[u][6]); a1[3] += bf2f(v[u][7]);
        }
    }

    #pragma unroll
    for (int j = 0; j < 4; j++) {
        a0[j] += __shfl_xor(a0[j], 16, 64);
        a0[j] += __shfl_xor(a0[j], 32, 64);
        a1[j] += __shfl_xor(a1[j], 16, 64);
        a1[j] += __shfl_xor(a1[j], 32, 64);
    }

    if (sub < 2) {
        const int q = c8 + sub * 4;
        f32x4_t s = sub ? a1 : a0;
        if (agg_out)
            *(f32x4_t*)(agg_out + (size_t)seg * FDIM + q) = s;
        if (fin_out) {
            f32x4_t xv = *(const f32x4_t*)(x + (size_t)seg * FDIM + q);
            f32x4_t gg = *(const f32x4_t*)(g + q);
            f32x4_t bt = *(const f32x4_t*)(bb + q);
            f32x4_t mn = *(const f32x4_t*)(mm + q);
            f32x4_t vr = *(const f32x4_t*)(vv + q);
            f32x4_t o;
            #pragma unroll
            for (int j = 0; j < 4; j++)
                o[j] = sigmoidf_((xv[j] - mn[j]) * (gg[j] * rsqrtf(vr[j] + BN_EPS))
                                 + bt[j] + s[j]);
            *(f32x4_t*)(fin_out + (size_t)seg * FDIM + q) = o;
        }
    }
}

extern "C" void kernel_launch(void* const* d_in, const int* in_sizes, int n_in,
                              void* d_out, int out_size, void* d_ws, size_t ws_size,
                              hipStream_t stream)
{
    const float* x0       = (const float*)d_in[0];
    const float* x1       = (const float*)d_in[1];
    const int*   node_idx = (const int*)d_in[2];
    const int*   edge_idx = (const int*)d_in[3];
    const float* W_nh     = (const float*)d_in[4];
    const float* b_nh     = (const float*)d_in[5];
    const float* W_en     = (const float*)d_in[6];
    const float* b_en     = (const float*)d_in[7];
    const float* bn0g = (const float*)d_in[8];
    const float* bn0b = (const float*)d_in[9];
    const float* bn0m = (const float*)d_in[10];
    const float* bn0v = (const float*)d_in[11];
    const float* bn1g = (const float*)d_in[12];
    const float* bn1b = (const float*)d_in[13];
    const float* bn1m = (const float*)d_in[14];
    const float* bn1v = (const float*)d_in[15];

    float* ws = (float*)d_ws;
    float* B    = ws;                           // node_msg_agg fp32 [20000,128]
    float* WTen = B + (size_t)NEDGES * FDIM;    // [256,128] fp32
    unsigned short* Wnh_bf = (unsigned short*)(WTen + 2 * FDIM * FDIM); // [128,128] bf16
    unsigned short* A_bf = Wnh_bf + FDIM * FDIM;                  // [100000,128] bf16
    unsigned short* D_bf = A_bf + (size_t)NNODES * FDIM;          // [20000,128] bf16
    int* off_ep = (int*)(D_bf + (size_t)NEDGES * FDIM);     // 160001 (pad 160004)
    int* off_n  = off_ep + 160004;                          // 100001 (pad 100004)
    unsigned* csr_e = (unsigned*)(off_n + 100004);          // 2M u32
    unsigned short* csr_n = (unsigned short*)(csr_e + NNZ_);// 2M u16
    unsigned* buck_e = (unsigned*)(csr_n + NNZ_);           // [NBUCK*CAP]
    unsigned* buck_n = buck_e + (size_t)NBUCK * CAP;        // [NBUCK*CAP]
    int* gcur_e = (int*)(buck_n + (size_t)NBUCK * CAP);     // 256
    int* gcur_n = gcur_e + NBUCK;                           // 256
    // partials overlay the (dead-after-sort) bucket arrays: [8][20000][128] fp32
    float* partial = (float*)buck_e;
    const size_t need = ((char*)partial - (char*)d_ws)
                      + (size_t)NPART * NEDGES * FDIM * sizeof(float);
    const bool big = ws_size >= need;

    // --- CSR build via 2-level bucket sort (edge dir binned by (e, n/PSLICE)) ---
    hipMemsetAsync(gcur_e, 0, 2 * NBUCK * sizeof(int), stream);
    bucket_scatter<<<(NNZ_ + 4095) / 4096, 1024, 0, stream>>>(
        node_idx, edge_idx, buck_e, buck_n, gcur_e, gcur_n);
    bucket_sort<<<2 * NBUCK, 256, 0, stream>>>(buck_e, buck_n, gcur_e, gcur_n,
                                               csr_e, csr_n, off_ep, off_n);

    prep_w<<<(3 * FDIM * FDIM + 255) / 256, 256, 0, stream>>>(W_nh, W_en, Wnh_bf, WTen);

    float* out0 = (float*)d_out;
    float* out1 = out0 + (size_t)NNODES * FDIM;

    // node -> hyperedge: GEMM1 (MFMA, bf16 out)
    gemm1_mfma<<<NNODES / 32, 256, 0, stream>>>(x0, Wnh_bf, b_nh, A_bf);

    if (big) {
        // XCD-affine partial gather -> streaming reduce (+ out1 finalize) -> GEMM2
        seg_part_gather<<<(NEDGES / 4) * 8, 256, 0, stream>>>(
            A_bf, csr_e, off_ep, partial);
        reduce_fin<<<(NEDGES * (FDIM / 4) + 255) / 256, 256, 0, stream>>>(
            partial, x1, bn1g, bn1b, bn1m, bn1v, B, out1);
    } else {
        // fallback: edge segments span 8 adjacent bins
        seg_sum_fin_v2<unsigned, 8, NPART><<<(NEDGES + 3) / 4, 256, 0, stream>>>(
            A_bf, csr_e, off_ep, x1, bn1g, bn1b, bn1m, bn1v, B, out1, NEDGES);
    }
    gemm_sig_bf16<<<NEDGES / 32, 256, 0, stream>>>(x1, B, WTen, b_en, D_bf);

    // hyperedge -> node: pull-aggregate (+ fused x0_out)
    seg_sum_fin_v2<unsigned short, 4, 1><<<(NNODES + 3) / 4, 256, 0, stream>>>(
        D_bf, csr_n, off_n, x0, bn0g, bn0b, bn0m, bn0v, nullptr, out0, NNODES);
}

// Round 5
// 384.881 us; speedup vs baseline: 1.1360x; 1.0507x over previous
//
#include <hip/hip_runtime.h>
#include <hip/hip_bf16.h>
#include <math.h>

#define NNODES 100000
#define NEDGES 20000
#define NNZ_   2000000
#define FDIM   128
#define BN_EPS 1e-5f

// ---- bucket-sort geometry (R1 verified) ----
#define NBUCK 256
#define CAP   9216        // per-bucket capacity (mean ~7812, sigma ~88 -> +16 sigma)
#define BPB_E 79          // bins/bucket, edge dir
#define BPB_N 391         // bins/bucket, node dir
#define SH_E  17          // edge entry = (e<<17)|n
#define SH_N  15          // node entry = (n<<15)|e

typedef __attribute__((ext_vector_type(8))) short bf16x8_t;
typedef __attribute__((ext_vector_type(4))) float f32x4_t;
typedef __attribute__((ext_vector_type(8))) unsigned short u16x8_t;

__device__ __forceinline__ float sigmoidf_(float x) {
    return 1.0f / (1.0f + __expf(-x));
}
__device__ __forceinline__ float bf2f(unsigned short u) {
    return __uint_as_float(((unsigned)u) << 16);
}
__device__ __forceinline__ unsigned short f2bf(float f) {
    __hip_bfloat16 h = __float2bfloat16(f);   // RNE
    return *reinterpret_cast<unsigned short*>(&h);
}

// ---- prep: bf16 W_nh + hi/lo-split bf16 halves of W_en ([n][k] layout) ----
__global__ __launch_bounds__(256) void prep_w(
    const float* __restrict__ W_nh, const float* __restrict__ W_en,
    unsigned short* __restrict__ Wnh_bf,
    unsigned short* __restrict__ W1hi, unsigned short* __restrict__ W1lo,
    unsigned short* __restrict__ W2hi, unsigned short* __restrict__ W2lo)
{
    int idx = blockIdx.x * blockDim.x + threadIdx.x;
    if (idx < FDIM * FDIM) {
        Wnh_bf[idx] = f2bf(W_nh[idx]);
        return;
    }
    int j = idx - FDIM * FDIM;
    if (j >= 2 * FDIM * FDIM) return;
    int n = j >> 8, kk = j & 255;
    float w = W_en[n * 2 * FDIM + kk];
    unsigned short hi = f2bf(w);
    unsigned short lo = f2bf(w - bf2f(hi));
    int o = n * FDIM + (kk & 127);
    if (kk < FDIM) { W1hi[o] = hi; W1lo[o] = lo; }
    else           { W2hi[o] = hi; W2lo[o] = lo; }
}

// ---- GEMM1 via MFMA: out[100000,128] = sigmoid(x0 @ W_nh^T + b), bf16 out ----
__global__ __launch_bounds__(256) void gemm1_mfma(
    const float* __restrict__ x0, const unsigned short* __restrict__ Wb,
    const float* __restrict__ bias, unsigned short* __restrict__ out)
{
    __shared__ unsigned short As[32][FDIM + 8];
    const int tid  = threadIdx.x;
    const int row0 = blockIdx.x * 32;
    {
        int r = tid >> 3, c0 = (tid & 7) * 16;
        const float* src = x0 + (size_t)(row0 + r) * FDIM + c0;
        unsigned short* dst = &As[r][c0];
        #pragma unroll
        for (int i = 0; i < 4; i++) {
            float4 v = *(const float4*)(src + i * 4);
            dst[i * 4 + 0] = f2bf(v.x);
            dst[i * 4 + 1] = f2bf(v.y);
            dst[i * 4 + 2] = f2bf(v.z);
            dst[i * 4 + 3] = f2bf(v.w);
        }
    }
    __syncthreads();
    const int wave  = tid >> 6;
    const int lane  = tid & 63;
    const int mhalf = wave & 1;
    const int nhalf = wave >> 1;
    const int lm    = lane & 15;
    const int quad  = lane >> 4;
    f32x4_t acc[4] = {};
    #pragma unroll
    for (int ks = 0; ks < 4; ks++) {
        bf16x8_t a = *(const bf16x8_t*)&As[mhalf * 16 + lm][ks * 32 + quad * 8];
        #pragma unroll
        for (int nt = 0; nt < 4; nt++) {
            int n = nhalf * 64 + nt * 16 + lm;
            bf16x8_t b = *(const bf16x8_t*)(Wb + (size_t)n * FDIM + ks * 32 + quad * 8);
            acc[nt] = __builtin_amdgcn_mfma_f32_16x16x32_bf16(a, b, acc[nt], 0, 0, 0);
        }
    }
    const int mbase = row0 + mhalf * 16 + quad * 4;
    #pragma unroll
    for (int nt = 0; nt < 4; nt++) {
        int n = nhalf * 64 + nt * 16 + lm;
        float bv = bias[n];
        #pragma unroll
        for (int r2 = 0; r2 < 4; r2++) {
            out[(size_t)(mbase + r2) * FDIM + n] = f2bf(sigmoidf_(acc[nt][r2] + bv));
        }
    }
}

// ---- GEMM2 via MFMA + bf16 error-compensated splitting ----
// D = sigmoid(x1@W1^T + B@W2^T + b), with
//   x1@W1 ~= x1hi@W1hi + x1lo@W1hi + x1hi@W1lo   (residual ~2^-18)
//   B @W2 ~= Bhi @W2hi + Blo @W2hi + Bhi @W2lo
// 6 MFMA passes of K=128 over one 32x128 tile; fp32 accumulation.
__global__ __launch_bounds__(256) void gemm2_mfma(
    const float* __restrict__ x1, const float* __restrict__ Bagg,
    const unsigned short* __restrict__ W1hi, const unsigned short* __restrict__ W1lo,
    const unsigned short* __restrict__ W2hi, const unsigned short* __restrict__ W2lo,
    const float* __restrict__ bias, unsigned short* __restrict__ out)
{
    __shared__ unsigned short Ax[2][32][FDIM + 8];   // x1 hi, lo
    __shared__ unsigned short Ab[2][32][FDIM + 8];   // B  hi, lo
    const int tid  = threadIdx.x;
    const int row0 = blockIdx.x * 32;
    {
        int r = tid >> 3, c0 = (tid & 7) * 16;
        const float* sx = x1   + (size_t)(row0 + r) * FDIM + c0;
        const float* sb = Bagg + (size_t)(row0 + r) * FDIM + c0;
        #pragma unroll
        for (int i = 0; i < 4; i++) {
            float4 v = *(const float4*)(sx + i * 4);
            float4 w = *(const float4*)(sb + i * 4);
            #pragma unroll
            for (int c = 0; c < 4; c++) {
                float fv = (c == 0) ? v.x : (c == 1) ? v.y : (c == 2) ? v.z : v.w;
                unsigned short h = f2bf(fv);
                Ax[0][r][c0 + i * 4 + c] = h;
                Ax[1][r][c0 + i * 4 + c] = f2bf(fv - bf2f(h));
                float fw = (c == 0) ? w.x : (c == 1) ? w.y : (c == 2) ? w.z : w.w;
                unsigned short hb = f2bf(fw);
                Ab[0][r][c0 + i * 4 + c] = hb;
                Ab[1][r][c0 + i * 4 + c] = f2bf(fw - bf2f(hb));
            }
        }
    }
    __syncthreads();
    const int wave  = tid >> 6;
    const int lane  = tid & 63;
    const int mhalf = wave & 1;
    const int nhalf = wave >> 1;
    const int lm    = lane & 15;
    const int quad  = lane >> 4;
    f32x4_t acc[4] = {};
    const unsigned short* Wsel[6] = {W1hi, W1hi, W1lo, W2hi, W2hi, W2lo};
    #pragma unroll
    for (int ps = 0; ps < 6; ps++) {
        const unsigned short (*Asel)[FDIM + 8] =
            (ps < 3) ? ((ps == 1) ? Ax[1] : Ax[0])
                     : ((ps == 4) ? Ab[1] : Ab[0]);
        const unsigned short* Wp = Wsel[ps];
        #pragma unroll
        for (int ks = 0; ks < 4; ks++) {
            bf16x8_t a = *(const bf16x8_t*)&Asel[mhalf * 16 + lm][ks * 32 + quad * 8];
            #pragma unroll
            for (int nt = 0; nt < 4; nt++) {
                int n = nhalf * 64 + nt * 16 + lm;
                bf16x8_t b = *(const bf16x8_t*)(Wp + (size_t)n * FDIM + ks * 32 + quad * 8);
                acc[nt] = __builtin_amdgcn_mfma_f32_16x16x32_bf16(a, b, acc[nt], 0, 0, 0);
            }
        }
    }
    const int mbase = row0 + mhalf * 16 + quad * 4;
    #pragma unroll
    for (int nt = 0; nt < 4; nt++) {
        int n = nhalf * 64 + nt * 16 + lm;
        float bv = bias[n];
        #pragma unroll
        for (int r2 = 0; r2 < 4; r2++) {
            out[(size_t)(mbase + r2) * FDIM + n] = f2bf(sigmoidf_(acc[nt][r2] + bv));
        }
    }
}

// ---- Pass A: coarse bucket partition (both directions in one pass) ----
__global__ __launch_bounds__(1024) void bucket_scatter(
    const int* __restrict__ ni, const int* __restrict__ ei,
    unsigned* __restrict__ buck_e, unsigned* __restrict__ buck_n,
    int* __restrict__ gcur_e, int* __restrict__ gcur_n)
{
    __shared__ int lh_e[NBUCK], lh_n[NBUCK], lb_e[NBUCK], lb_n[NBUCK];
    const int t = threadIdx.x;
    if (t < NBUCK) { lh_e[t] = 0; lh_n[t] = 0; }
    __syncthreads();
    unsigned ent_e[4], ent_n[4];
    int be[4], bn[4], re[4], rn[4];
    const int base = blockIdx.x * 4096;
    #pragma unroll
    for (int j = 0; j < 4; j++) {
        int i = base + j * 1024 + t;
        if (i < NNZ_) {
            unsigned n = (unsigned)ni[i], e = (unsigned)ei[i];
            ent_e[j] = (e << SH_E) | n;  be[j] = (int)(e / BPB_E);
            ent_n[j] = (n << SH_N) | e;  bn[j] = (int)(n / BPB_N);
            re[j] = atomicAdd(&lh_e[be[j]], 1);
            rn[j] = atomicAdd(&lh_n[bn[j]], 1);
        } else { be[j] = -1; }
    }
    __syncthreads();
    if (t < NBUCK) {
        lb_e[t] = t * CAP + atomicAdd(&gcur_e[t], lh_e[t]);
        lb_n[t] = t * CAP + atomicAdd(&gcur_n[t], lh_n[t]);
    }
    __syncthreads();
    #pragma unroll
    for (int j = 0; j < 4; j++) {
        if (be[j] >= 0) {
            buck_e[(size_t)lb_e[be[j]] + re[j]] = ent_e[j];
            buck_n[(size_t)lb_n[bn[j]] + rn[j]] = ent_n[j];
        }
    }
}

// ---- Pass B: sort one bucket into its compact region (R1 verified) ----
template<int BPB, int SH, unsigned MASK, int NBINS, typename OUT>
__device__ __forceinline__ void sort_bucket(
    const unsigned* __restrict__ region, int cnt, int gbase, int b0,
    OUT* __restrict__ csr, int* __restrict__ off)
{
    __shared__ unsigned lh[512];
    __shared__ unsigned lw[4];
    const int t = threadIdx.x;
    lh[t] = 0; lh[t + 256] = 0;
    __syncthreads();
    for (int i = t; i < cnt; i += 256) {
        int bin = (int)(region[i] >> SH) - b0;
        atomicAdd(&lh[bin], 1u);
    }
    __syncthreads();
    unsigned h0 = lh[2 * t], h1 = lh[2 * t + 1];
    unsigned s = h0 + h1, inc = s;
    const int lane = t & 63;
    #pragma unroll
    for (int d = 1; d <= 32; d <<= 1) {
        unsigned v = (unsigned)__shfl_up((int)inc, d, 64);
        if (lane >= d) inc += v;
    }
    if (lane == 63) lw[t >> 6] = inc;
    __syncthreads();
    unsigned pre = 0;
    #pragma unroll
    for (int w = 0; w < 4; w++) if (w < (t >> 6)) pre += lw[w];
    unsigned excl = pre + inc - s;
    unsigned c0 = (unsigned)gbase + excl;
    unsigned c1 = c0 + h0;
    lh[2 * t] = c0; lh[2 * t + 1] = c1;
    int i0 = 2 * t, i1 = 2 * t + 1;
    if (i0 <= BPB && b0 + i0 <= NBINS) off[b0 + i0] = (int)c0;
    if (i1 <= BPB && b0 + i1 <= NBINS) off[b0 + i1] = (int)c1;
    __syncthreads();
    for (int i = t; i < cnt; i += 256) {
        unsigned ent = region[i];
        int bin = (int)(ent >> SH) - b0;
        unsigned pos = atomicAdd(&lh[bin], 1u);
        csr[pos] = (OUT)(ent & MASK);
    }
}

__global__ __launch_bounds__(256) void bucket_sort(
    const unsigned* __restrict__ buck_e, const unsigned* __restrict__ buck_n,
    const int* __restrict__ gcur_e, const int* __restrict__ gcur_n,
    unsigned* __restrict__ csr_e, unsigned short* __restrict__ csr_n,
    int* __restrict__ off_e, int* __restrict__ off_n)
{
    const int b = blockIdx.x & 255;
    const int* gc = (blockIdx.x < 256) ? gcur_e : gcur_n;
    __shared__ int ws4[4];
    const int t = threadIdx.x;
    int v = (t < b) ? gc[t] : 0;
    #pragma unroll
    for (int d = 32; d > 0; d >>= 1) v += __shfl_down(v, d, 64);
    if ((t & 63) == 0) ws4[t >> 6] = v;
    __syncthreads();
    const int gbase = ws4[0] + ws4[1] + ws4[2] + ws4[3];
    const int cnt = gc[b];
    __syncthreads();
    if (blockIdx.x < 256)
        sort_bucket<BPB_E, SH_E, 0x1FFFFu, NEDGES, unsigned>(
            buck_e + (size_t)b * CAP, cnt, gbase, b * BPB_E, csr_e, off_e);
    else
        sort_bucket<BPB_N, SH_N, 0x7FFFu, NNODES, unsigned short>(
            buck_n + (size_t)b * CAP, cnt, gbase, b * BPB_N, csr_n, off_n);
}

// ---- segmented sum v2: one wave per segment, 16B gathers, deep ILP (R1) ----
template<typename IDX, int U>
__global__ __launch_bounds__(256) void seg_sum_fin_v2(
    const unsigned short* __restrict__ table, const IDX* __restrict__ csr,
    const int* __restrict__ off, const float* __restrict__ x,
    const float* __restrict__ g, const float* __restrict__ bb,
    const float* __restrict__ mm, const float* __restrict__ vv,
    float* __restrict__ agg_out, float* __restrict__ fin_out, int nseg)
{
    const int seg = blockIdx.x * 4 + (threadIdx.x >> 6);
    if (seg >= nseg) return;
    const int lane = threadIdx.x & 63;
    const int c    = lane & 15;
    const int sub  = lane >> 4;
    const int c8   = c * 8;

    const int i0 = off[seg], i1 = off[seg + 1];
    f32x4_t a0 = {}, a1 = {};

    int i = i0;
    for (; i + 4 * U <= i1; i += 4 * U) {
        int r[U];
        u16x8_t v[U];
        #pragma unroll
        for (int u = 0; u < U; u++) r[u] = (int)csr[i + 4 * u + sub];
        #pragma unroll
        for (int u = 0; u < U; u++)
            v[u] = *(const u16x8_t*)(table + (size_t)r[u] * FDIM + c8);
        #pragma unroll
        for (int u = 0; u < U; u++) {
            a0[0] += bf2f(v[u][0]); a0[1] += bf2f(v[u][1]);
            a0[2] += bf2f(v[u][2]); a0[3] += bf2f(v[u][3]);
            a1[0] += bf2f(v[u][4]); a1[1] += bf2f(v[u][5]);
            a1[2] += bf2f(v[u][6]); a1[3] += bf2f(v[u][7]);
        }
    }
    if (i < i1) {
        u16x8_t v[U];
        #pragma unroll
        for (int u = 0; u < U; u++) {
            int row = i + 4 * u + sub;
            u16x8_t z = {};
            v[u] = z;
            if (row < i1)
                v[u] = *(const u16x8_t*)(table + (size_t)csr[row] * FDIM + c8);
        }
        #pragma unroll
        for (int u = 0; u < U; u++) {
            a0[0] += bf2f(v[u][0]); a0[1] += bf2f(v[u][1]);
            a0[2] += bf2f(v[u][2]); a0[3] += bf2f(v[u][3]);
            a1[0] += bf2f(v[u][4]); a1[1] += bf2f(v[u][5]);
            a1[2] += bf2f(v[u][6]); a1[3] += bf2f(v[u][7]);
        }
    }

    #pragma unroll
    for (int j = 0; j < 4; j++) {
        a0[j] += __shfl_xor(a0[j], 16, 64);
        a0[j] += __shfl_xor(a0[j], 32, 64);
        a1[j] += __shfl_xor(a1[j], 16, 64);
        a1[j] += __shfl_xor(a1[j], 32, 64);
    }

    if (sub < 2) {
        const int q = c8 + sub * 4;
        f32x4_t s = sub ? a1 : a0;
        if (agg_out)
            *(f32x4_t*)(agg_out + (size_t)seg * FDIM + q) = s;
        if (fin_out) {
            f32x4_t xv = *(const f32x4_t*)(x + (size_t)seg * FDIM + q);
            f32x4_t gg = *(const f32x4_t*)(g + q);
            f32x4_t bt = *(const f32x4_t*)(bb + q);
            f32x4_t mn = *(const f32x4_t*)(mm + q);
            f32x4_t vr = *(const f32x4_t*)(vv + q);
            f32x4_t o;
            #pragma unroll
            for (int j = 0; j < 4; j++)
                o[j] = sigmoidf_((xv[j] - mn[j]) * (gg[j] * rsqrtf(vr[j] + BN_EPS))
                                 + bt[j] + s[j]);
            *(f32x4_t*)(fin_out + (size_t)seg * FDIM + q) = o;
        }
    }
}

extern "C" void kernel_launch(void* const* d_in, const int* in_sizes, int n_in,
                              void* d_out, int out_size, void* d_ws, size_t ws_size,
                              hipStream_t stream)
{
    const float* x0       = (const float*)d_in[0];
    const float* x1       = (const float*)d_in[1];
    const int*   node_idx = (const int*)d_in[2];
    const int*   edge_idx = (const int*)d_in[3];
    const float* W_nh     = (const float*)d_in[4];
    const float* b_nh     = (const float*)d_in[5];
    const float* W_en     = (const float*)d_in[6];
    const float* b_en     = (const float*)d_in[7];
    const float* bn0g = (const float*)d_in[8];
    const float* bn0b = (const float*)d_in[9];
    const float* bn0m = (const float*)d_in[10];
    const float* bn0v = (const float*)d_in[11];
    const float* bn1g = (const float*)d_in[12];
    const float* bn1b = (const float*)d_in[13];
    const float* bn1m = (const float*)d_in[14];
    const float* bn1v = (const float*)d_in[15];

    float* ws = (float*)d_ws;
    float* B = ws;                                        // node_msg_agg fp32 [20000,128]
    unsigned short* Wnh_bf = (unsigned short*)(B + (size_t)NEDGES * FDIM); // [128,128] bf16
    unsigned short* W1hi = Wnh_bf + FDIM * FDIM;
    unsigned short* W1lo = W1hi + FDIM * FDIM;
    unsigned short* W2hi = W1lo + FDIM * FDIM;
    unsigned short* W2lo = W2hi + FDIM * FDIM;
    unsigned short* A_bf = W2lo + FDIM * FDIM;            // [100000,128] bf16
    unsigned short* D_bf = A_bf + (size_t)NNODES * FDIM;  // [20000,128] bf16
    int* off_e = (int*)(D_bf + (size_t)NEDGES * FDIM);    // 20001 (pad 20004)
    int* off_n = off_e + 20004;                           // 100001 (pad 100004)
    unsigned* csr_e = (unsigned*)(off_n + 100004);        // 2M u32
    unsigned short* csr_n = (unsigned short*)(csr_e + NNZ_); // 2M u16
    unsigned* buck_e = (unsigned*)(csr_n + NNZ_);         // [NBUCK*CAP]
    unsigned* buck_n = buck_e + (size_t)NBUCK * CAP;      // [NBUCK*CAP]
    int* gcur_e = (int*)(buck_n + (size_t)NBUCK * CAP);   // 256
    int* gcur_n = gcur_e + NBUCK;                         // 256

    // --- CSR build via 2-level bucket sort ---
    hipMemsetAsync(gcur_e, 0, 2 * NBUCK * sizeof(int), stream);
    bucket_scatter<<<(NNZ_ + 4095) / 4096, 1024, 0, stream>>>(
        node_idx, edge_idx, buck_e, buck_n, gcur_e, gcur_n);
    bucket_sort<<<2 * NBUCK, 256, 0, stream>>>(buck_e, buck_n, gcur_e, gcur_n,
                                               csr_e, csr_n, off_e, off_n);

    prep_w<<<(3 * FDIM * FDIM + 255) / 256, 256, 0, stream>>>(
        W_nh, W_en, Wnh_bf, W1hi, W1lo, W2hi, W2lo);

    float* out0 = (float*)d_out;
    float* out1 = out0 + (size_t)NNODES * FDIM;

    // node -> hyperedge: GEMM1 (MFMA, bf16 out) then pull-aggregate (+ fused x1_out)
    gemm1_mfma<<<NNODES / 32, 256, 0, stream>>>(x0, Wnh_bf, b_nh, A_bf);
    seg_sum_fin_v2<unsigned, 8><<<(NEDGES + 3) / 4, 256, 0, stream>>>(
        A_bf, csr_e, off_e, x1, bn1g, bn1b, bn1m, bn1v, B, out1, NEDGES);

    // hyperedge -> node: GEMM2 (MFMA, split-bf16 fp32-accurate) then pull-aggregate
    gemm2_mfma<<<NEDGES / 32, 256, 0, stream>>>(
        x1, B, W1hi, W1lo, W2hi, W2lo, b_en, D_bf);
    seg_sum_fin_v2<unsigned short, 4><<<(NNODES + 3) / 4, 256, 0, stream>>>(
        D_bf, csr_n, off_n, x0, bn0g, bn0b, bn0m, bn0v, nullptr, out0, NNODES);
}